// Round 7
// baseline (188.872 us; speedup 1.0000x reference)
//
#include <hip/hip_runtime.h>

#define S_LEN 2048
#define DM 1024
#define NH 16
#define HD 64
#define QKV_LD 3072

using f32x4 = __attribute__((ext_vector_type(4))) float;
using s16x8 = __attribute__((ext_vector_type(8))) short;

__device__ __forceinline__ unsigned short f2bf(float f) {
  union { float f; unsigned u; } v; v.f = f;
  unsigned r = v.u + 0x7fffu + ((v.u >> 16) & 1u);
  return (unsigned short)(r >> 16);
}

__device__ __forceinline__ float bf2f(unsigned short u) {
  union { unsigned u; float f; } v; v.u = ((unsigned)u) << 16;
  return v.f;
}

__device__ __forceinline__ void gload_lds16(const void* g, void* l) {
  __builtin_amdgcn_global_load_lds(
      (const __attribute__((address_space(1))) void*)g,
      (__attribute__((address_space(3))) void*)l, 16, 0, 0);
}

__global__ __launch_bounds__(256) void cvt_f32_bf16(const float* __restrict__ in,
                                                    unsigned short* __restrict__ out,
                                                    int n) {
  int i = (blockIdx.x * 256 + threadIdx.x) * 8;
  if (i >= n) return;
  float4 a = *(const float4*)(in + i);
  float4 b = *(const float4*)(in + i + 4);
  s16x8 o;
  o[0] = f2bf(a.x); o[1] = f2bf(a.y); o[2] = f2bf(a.z); o[3] = f2bf(a.w);
  o[4] = f2bf(b.x); o[5] = f2bf(b.y); o[6] = f2bf(b.z); o[7] = f2bf(b.w);
  *(s16x8*)(out + i) = o;
}

// C[M,N] = A[M,K] * W[N,K]^T, bf16 in, bf16 or f32 out. 128x128 tile, BK=64,
// 4 waves (2x2), 16x16x32 MFMA, global_load_lds staging (m97 structure).
template <bool OUT_F32>
__global__ __launch_bounds__(256, 2) void gemm_bt(const unsigned short* __restrict__ A,
                                                  const unsigned short* __restrict__ W,
                                                  void* __restrict__ Cout,
                                                  int M, int N, int K, int nbn) {
  __shared__ unsigned short As[128 * 64];
  __shared__ unsigned short Bs[128 * 64];
  const int bm = blockIdx.x / nbn, bn = blockIdx.x % nbn;
  const int tid = threadIdx.x;
  const int w = tid >> 6, lane = tid & 63;
  const int wr = w >> 1, wc = w & 1;
  const int lr = lane & 15, lk = lane >> 4;
  const int m0 = bm * 128, n0 = bn * 128;
  f32x4 acc[4][4] = {};

  for (int k0 = 0; k0 < K; k0 += 64) {
#pragma unroll
    for (int i = 0; i < 4; ++i) {
      const int base = i * 4096 + w * 1024;
      const int boff = base + lane * 16;
      const int row = boff >> 7;
      const int col = (boff >> 1) & 63;
      gload_lds16(A + (size_t)(m0 + row) * K + k0 + col, (char*)As + base);
      gload_lds16(W + (size_t)(n0 + row) * K + k0 + col, (char*)Bs + base);
    }
    __syncthreads();
#pragma unroll
    for (int kk = 0; kk < 2; ++kk) {
      s16x8 af[4], bfr[4];
#pragma unroll
      for (int m = 0; m < 4; ++m)
        af[m] = *(const s16x8*)((const char*)As + (wr * 64 + m * 16 + lr) * 128 + kk * 64 + lk * 16);
#pragma unroll
      for (int n = 0; n < 4; ++n)
        bfr[n] = *(const s16x8*)((const char*)Bs + (wc * 64 + n * 16 + lr) * 128 + kk * 64 + lk * 16);
#pragma unroll
      for (int m = 0; m < 4; ++m)
#pragma unroll
        for (int n = 0; n < 4; ++n)
          acc[m][n] = __builtin_amdgcn_mfma_f32_16x16x32_bf16(af[m], bfr[n], acc[m][n], 0, 0, 0);
    }
    __syncthreads();
  }
#pragma unroll
  for (int m = 0; m < 4; ++m)
#pragma unroll
    for (int n = 0; n < 4; ++n)
#pragma unroll
      for (int r = 0; r < 4; ++r) {
        const int row = m0 + wr * 64 + m * 16 + lk * 4 + r;
        const int col = n0 + wc * 64 + n * 16 + lr;
        if (OUT_F32)
          ((float*)Cout)[(size_t)row * N + col] = acc[m][n][r];
        else
          ((unsigned short*)Cout)[(size_t)row * N + col] = f2bf(acc[m][n][r]);
      }
}

// Transpose V out of qkv into VT[bh][d][s].
__global__ __launch_bounds__(256) void vtrans(const unsigned short* __restrict__ qkv,
                                              unsigned short* __restrict__ vt) {
  __shared__ unsigned short T[64][65];
  const int blk = blockIdx.x;
  const int st = blk & 31, bh = blk >> 5;
  const int h = bh & 15, b = bh >> 4;
  const int s0 = st * 64;
  const int tid = threadIdx.x;
#pragma unroll
  for (int i = 0; i < 2; ++i) {
    const int idx = tid + i * 256;
    const int sy = idx >> 3, tx = idx & 7;
    s16x8 v = *(const s16x8*)(qkv + (size_t)(b * S_LEN + s0 + sy) * QKV_LD + 2 * DM + h * HD + tx * 8);
#pragma unroll
    for (int j = 0; j < 8; ++j) T[tx * 8 + j][sy] = v[j];
  }
  __syncthreads();
#pragma unroll
  for (int i = 0; i < 2; ++i) {
    const int idx = tid + i * 256;
    const int d = idx >> 3, tx = idx & 7;
    s16x8 v;
#pragma unroll
    for (int j = 0; j < 8; ++j) v[j] = T[d][tx * 8 + j];
    *(s16x8*)(vt + (size_t)bh * (HD * S_LEN) + (size_t)d * S_LEN + s0 + tx * 8) = v;
  }
}

// Flash attention, causal. Block = 64 q-rows (4 waves x 16); K/V tiles staged
// to LDS, DOUBLE-BUFFERED (T3-minimum recipe): stage(t+1) issued at top of
// iteration t, ONE __syncthreads per tile (its implicit vmcnt(0) drain lands
// after the whole compute phase -> staging latency hidden). Swapped QK^T
// (mfma(K,Q) -> S^T): in-lane softmax, q-index = lr. T5 setprio around MFMA.
__global__ __launch_bounds__(256, 3) void attn_fwd(const unsigned short* __restrict__ qkv,
                                                   const unsigned short* __restrict__ vt,
                                                   unsigned short* __restrict__ aout) {
  __shared__ unsigned short Ks[2][64 * 64];   // [s][d] 128B rows, swizzled chunks
  __shared__ unsigned short Vs[2][64 * 64];   // [d][s] 128B rows, swizzled chunks
  __shared__ unsigned short Pbuf[4][16][72];  // per-wave P re-layout
  const int bid = blockIdx.x;
  const int qt = 31 - (bid >> 5);  // heavy q-tiles first
  const int bh = bid & 31;
  const int h = bh & 15, b = bh >> 4;
  const int tid = threadIdx.x, w = tid >> 6, lane = tid & 63;
  const int lr = lane & 15, lk = lane >> 4;
  const int qb = qt * 64 + w * 16;
  const size_t rowbase = (size_t)b * S_LEN;
  const unsigned short* kbase = qkv + rowbase * QKV_LD + DM + h * HD;
  const unsigned short* vbase = vt + (size_t)bh * (HD * S_LEN);

  // staging lane geometry: each gload_lds16 instr covers 8 rows x 128B
  const int r8 = lane >> 3, c8 = lane & 7;
  const int celem = ((c8 ^ r8) << 3);  // inverse-swizzled element offset in row
  // swizzled read offsets (elements): e ^ ((row&7)<<3), row&7 == lr&7
  const int swz = (lr & 7) << 3;

  // Q fragments (B-operand), scaled by 0.125*log2(e) -> exp2-domain softmax
  s16x8 qf[2];
#pragma unroll
  for (int dk = 0; dk < 2; ++dk) {
    s16x8 q = *(const s16x8*)(qkv + (rowbase + qb + lr) * QKV_LD + h * HD + dk * 32 + lk * 8);
#pragma unroll
    for (int j = 0; j < 8; ++j)
      q[j] = (short)f2bf(bf2f((unsigned short)q[j]) * 0.18033688011112042f);
    qf[dk] = q;
  }

  f32x4 oacc[4] = {};
  float mr = -1e30f, ls = 0.f;

  auto stage = [&](int t, int c) {
    const int k0 = t * 64;
#pragma unroll
    for (int jj = 0; jj < 4; ++jj) {
      const int j = w * 4 + jj;
      if (j < 8)
        gload_lds16(kbase + (size_t)(k0 + j * 8 + r8) * QKV_LD + celem,
                    (char*)Ks[c] + j * 1024);
      else
        gload_lds16(vbase + (size_t)((j - 8) * 8 + r8) * S_LEN + k0 + celem,
                    (char*)Vs[c] + (j - 8) * 1024);
    }
  };

  stage(0, 0);
  __syncthreads();  // implicit vmcnt(0): tile 0 resident
  int c = 0;

  for (int t = 0; t <= qt; ++t) {
    const int k0 = t * 64;
    // prefetch next tile into the other buffer; drained by END-of-iter barrier
    if (t < qt) stage(t + 1, c ^ 1);

    // ---- S^T = K Q^T : sf[n][r] = S[k = k0+n*16+lk*4+r][q = qb+lr] ----
    const bool dtile = (t == qt);
    f32x4 sf[4];
    __builtin_amdgcn_s_setprio(1);
#pragma unroll
    for (int n = 0; n < 4; ++n) {
      if (!dtile || n <= w) {
        s16x8 kf0 = *(const s16x8*)(Ks[c] + (n * 16 + lr) * 64 + ((lk * 8) ^ swz));
        s16x8 kf1 = *(const s16x8*)(Ks[c] + (n * 16 + lr) * 64 + ((32 + lk * 8) ^ swz));
        f32x4 s = {};
        s = __builtin_amdgcn_mfma_f32_16x16x32_bf16(kf0, qf[0], s, 0, 0, 0);
        s = __builtin_amdgcn_mfma_f32_16x16x32_bf16(kf1, qf[1], s, 0, 0, 0);
        sf[n] = s;
      } else {
#pragma unroll
        for (int r = 0; r < 4; ++r) sf[n][r] = -1e30f;
      }
    }
    __builtin_amdgcn_s_setprio(0);
    if (dtile) {  // diagonal subtile n==w: mask k > q, i.e. lk*4+r > lr
#pragma unroll
      for (int r = 0; r < 4; ++r)
        if (lk * 4 + r > lr) sf[w][r] = -1e30f;
    }
    // ---- online softmax (q per-lane = lr): in-lane reduce + 2 shfl ----
    float pm = sf[0][0];
#pragma unroll
    for (int n = 0; n < 4; ++n)
#pragma unroll
      for (int r = 0; r < 4; ++r) pm = fmaxf(pm, sf[n][r]);
    pm = fmaxf(pm, __shfl_xor(pm, 16));
    pm = fmaxf(pm, __shfl_xor(pm, 32));
    if (__any(pm > mr + 8.f)) {  // defer-max (T13)
      const float mn = fmaxf(mr, pm);
      const float al = __builtin_amdgcn_exp2f(mr - mn);
      mr = mn;
      ls *= al;
#pragma unroll
      for (int r = 0; r < 4; ++r) {
        const float alq = __shfl(al, lk * 4 + r);
#pragma unroll
        for (int n = 0; n < 4; ++n) oacc[n][r] *= alq;
      }
    }
    float rs = 0.f;
#pragma unroll
    for (int n = 0; n < 4; ++n)
#pragma unroll
      for (int r = 0; r < 4; ++r) {
        const float p = __builtin_amdgcn_exp2f(sf[n][r] - mr);
        sf[n][r] = p;
        rs += p;
      }
    rs += __shfl_xor(rs, 16);
    rs += __shfl_xor(rs, 32);
    ls += rs;
    // pack P -> Pbuf[q=lr][k] (positive values: round-half-up ~= RNE)
#pragma unroll
    for (int n = 0; n < 4; ++n) {
      union { float f; unsigned u; } c0, c1, c2, c3;
      c0.f = sf[n][0]; c1.f = sf[n][1]; c2.f = sf[n][2]; c3.f = sf[n][3];
      uint2 pk;
      pk.x = ((c0.u + 0x8000u) >> 16) | (((c1.u + 0x8000u) >> 16) << 16);
      pk.y = ((c2.u + 0x8000u) >> 16) | (((c3.u + 0x8000u) >> 16) << 16);
      *(uint2*)&Pbuf[w][lr][n * 16 + lk * 4] = pk;
    }
    // ---- O += P V : A = P rows (Pbuf), B = V^T rows (Vs, swizzled) ----
    __builtin_amdgcn_s_setprio(1);
#pragma unroll
    for (int kk = 0; kk < 2; ++kk) {
      s16x8 pf = *(const s16x8*)&Pbuf[w][lr][kk * 32 + lk * 8];
#pragma unroll
      for (int n = 0; n < 4; ++n) {
        s16x8 vf = *(const s16x8*)(Vs[c] + (n * 16 + lr) * 64 + ((kk * 32 + lk * 8) ^ swz));
        oacc[n] = __builtin_amdgcn_mfma_f32_16x16x32_bf16(pf, vf, oacc[n], 0, 0, 0);
      }
    }
    __builtin_amdgcn_s_setprio(0);
    __syncthreads();  // single barrier/tile: drains prefetch (vmcnt 0) + WAR
    c ^= 1;
  }

  // epilogue: O/l ; l is in q=lr domain, O rows are q=lk*4+r
  const float rl = __builtin_amdgcn_rcpf(ls);
#pragma unroll
  for (int r = 0; r < 4; ++r) {
    const float rlq = __shfl(rl, lk * 4 + r);
#pragma unroll
    for (int n = 0; n < 4; ++n)
      aout[(rowbase + qb + lk * 4 + r) * DM + h * HD + n * 16 + lr] = f2bf(oacc[n][r] * rlq);
  }
}

extern "C" void kernel_launch(void* const* d_in, const int* in_sizes, int n_in,
                              void* d_out, int out_size, void* d_ws, size_t ws_size,
                              hipStream_t stream) {
  const float* x = (const float*)d_in[0];      // [2,2048,1024]
  const float* wqkv = (const float*)d_in[1];   // [3072,1024]
  const float* wproj = (const float*)d_in[2];  // [1024,1024]
  float* out = (float*)d_out;                  // [2,2048,1024] f32

  char* ws = (char*)d_ws;
  unsigned short* xb = (unsigned short*)ws;                     // dead after gemm1
  unsigned short* wqkvb = (unsigned short*)(ws + (8u << 20));   // dead after gemm1
  unsigned short* wprojb = (unsigned short*)(ws + (14u << 20)); // written after attn
  unsigned short* vtb = (unsigned short*)ws;                    // overlays xb/wqkvb
  unsigned short* qkvb = (unsigned short*)(ws + (16u << 20));
  unsigned short* attnb = (unsigned short*)(ws + (40u << 20));

  cvt_f32_bf16<<<2048, 256, 0, stream>>>(x, xb, 4096 * 1024);
  cvt_f32_bf16<<<1536, 256, 0, stream>>>(wqkv, wqkvb, 3072 * 1024);

  gemm_bt<false><<<32 * 24, 256, 0, stream>>>(xb, wqkvb, qkvb, 4096, 3072, 1024, 24);
  vtrans<<<1024, 256, 0, stream>>>(qkvb, vtb);
  attn_fwd<<<1024, 256, 0, stream>>>(qkvb, vtb, attnb);
  cvt_f32_bf16<<<512, 256, 0, stream>>>(wproj, wprojb, 1024 * 1024);
  gemm_bt<true><<<32 * 8, 256, 0, stream>>>(attnb, wprojb, out, 4096, 1024, 1024, 8);
}

// Round 8
// 182.412 us; speedup vs baseline: 1.0354x; 1.0354x over previous
//
#include <hip/hip_runtime.h>

#define S_LEN 2048
#define DM 1024
#define NH 16
#define HD 64
#define QKV_LD 3072

using f32x4 = __attribute__((ext_vector_type(4))) float;
using s16x8 = __attribute__((ext_vector_type(8))) short;

__device__ __forceinline__ unsigned short f2bf(float f) {
  union { float f; unsigned u; } v; v.f = f;
  unsigned r = v.u + 0x7fffu + ((v.u >> 16) & 1u);
  return (unsigned short)(r >> 16);
}

__device__ __forceinline__ float bf2f(unsigned short u) {
  union { unsigned u; float f; } v; v.u = ((unsigned)u) << 16;
  return v.f;
}

__device__ __forceinline__ void gload_lds16(const void* g, void* l) {
  __builtin_amdgcn_global_load_lds(
      (const __attribute__((address_space(1))) void*)g,
      (__attribute__((address_space(3))) void*)l, 16, 0, 0);
}

// bijective XCD-aware swizzle (T1); requires nwg % 8 == 0
__device__ __forceinline__ int xcd_swz(int bid, int nwg) {
  const int cpx = nwg >> 3;
  return (bid & 7) * cpx + (bid >> 3);
}

__global__ __launch_bounds__(256) void cvt_f32_bf16(const float* __restrict__ in,
                                                    unsigned short* __restrict__ out,
                                                    int n) {
  int i = (blockIdx.x * 256 + threadIdx.x) * 8;
  if (i >= n) return;
  float4 a = *(const float4*)(in + i);
  float4 b = *(const float4*)(in + i + 4);
  s16x8 o;
  o[0] = f2bf(a.x); o[1] = f2bf(a.y); o[2] = f2bf(a.z); o[3] = f2bf(a.w);
  o[4] = f2bf(b.x); o[5] = f2bf(b.y); o[6] = f2bf(b.z); o[7] = f2bf(b.w);
  *(s16x8*)(out + i) = o;
}

// C[M,N] = A[M,K] * W[N,K]^T, bf16 in, bf16 or f32 out. 128xBN tile, BK=64,
// 4 waves (2x2), 16x16x32 MFMA, global_load_lds staging (m97 structure).
// launch_bounds(256,3): 3 blocks/CU co-residency hides the barrier drain.
template <int BN, bool OUT_F32>
__global__ __launch_bounds__(256, 3) void gemm_bt(const unsigned short* __restrict__ A,
                                                  const unsigned short* __restrict__ W,
                                                  void* __restrict__ Cout,
                                                  int M, int N, int K, int nbn) {
  constexpr int FN = BN / 32;            // per-wave n-fragments
  constexpr int ROUNDS = (128 + BN) / 32;  // 4KB staging rounds
  __shared__ unsigned short As[128 * 64];
  __shared__ unsigned short Bs[BN * 64];
  const int bid = xcd_swz(blockIdx.x, gridDim.x);
  const int bm = bid / nbn, bn = bid % nbn;
  const int tid = threadIdx.x;
  const int w = tid >> 6, lane = tid & 63;
  const int wr = w >> 1, wc = w & 1;
  const int lr = lane & 15, lk = lane >> 4;
  const int m0 = bm * 128, n0 = bn * BN;
  f32x4 acc[4][FN] = {};

  for (int k0 = 0; k0 < K; k0 += 64) {
#pragma unroll
    for (int j = 0; j < ROUNDS; ++j) {
      const int base = j * 4096 + w * 1024;  // wave-uniform byte offset
      const int boff = base + lane * 16;
      const int row = boff >> 7;             // 128 B per row (64 bf16)
      const int col = (boff >> 1) & 63;
      if (j < 4)
        gload_lds16(A + (size_t)(m0 + row) * K + k0 + col, (char*)As + base);
      else
        gload_lds16(W + (size_t)(n0 + row - 128) * K + k0 + col,
                    (char*)Bs + base - 16384);
    }
    __syncthreads();
#pragma unroll
    for (int kk = 0; kk < 2; ++kk) {
      s16x8 af[4], bfr[FN];
#pragma unroll
      for (int m = 0; m < 4; ++m)
        af[m] = *(const s16x8*)((const char*)As + (wr * 64 + m * 16 + lr) * 128 + kk * 64 + lk * 16);
#pragma unroll
      for (int n = 0; n < FN; ++n)
        bfr[n] = *(const s16x8*)((const char*)Bs + (wc * (FN * 16) + n * 16 + lr) * 128 + kk * 64 + lk * 16);
#pragma unroll
      for (int m = 0; m < 4; ++m)
#pragma unroll
        for (int n = 0; n < FN; ++n)
          acc[m][n] = __builtin_amdgcn_mfma_f32_16x16x32_bf16(af[m], bfr[n], acc[m][n], 0, 0, 0);
    }
    __syncthreads();
  }
#pragma unroll
  for (int m = 0; m < 4; ++m)
#pragma unroll
    for (int n = 0; n < FN; ++n)
#pragma unroll
      for (int r = 0; r < 4; ++r) {
        const int row = m0 + wr * 64 + m * 16 + lk * 4 + r;
        const int col = n0 + wc * (FN * 16) + n * 16 + lr;
        if (OUT_F32)
          ((float*)Cout)[(size_t)row * N + col] = acc[m][n][r];
        else
          ((unsigned short*)Cout)[(size_t)row * N + col] = f2bf(acc[m][n][r]);
      }
}

// Transpose V out of qkv into VT[bh][d][s].
__global__ __launch_bounds__(256) void vtrans(const unsigned short* __restrict__ qkv,
                                              unsigned short* __restrict__ vt) {
  __shared__ unsigned short T[64][65];
  const int blk = blockIdx.x;
  const int st = blk & 31, bh = blk >> 5;
  const int h = bh & 15, b = bh >> 4;
  const int s0 = st * 64;
  const int tid = threadIdx.x;
#pragma unroll
  for (int i = 0; i < 2; ++i) {
    const int idx = tid + i * 256;
    const int sy = idx >> 3, tx = idx & 7;
    s16x8 v = *(const s16x8*)(qkv + (size_t)(b * S_LEN + s0 + sy) * QKV_LD + 2 * DM + h * HD + tx * 8);
#pragma unroll
    for (int j = 0; j < 8; ++j) T[tx * 8 + j][sy] = v[j];
  }
  __syncthreads();
#pragma unroll
  for (int i = 0; i < 2; ++i) {
    const int idx = tid + i * 256;
    const int d = idx >> 3, tx = idx & 7;
    s16x8 v;
#pragma unroll
    for (int j = 0; j < 8; ++j) v[j] = T[d][tx * 8 + j];
    *(s16x8*)(vt + (size_t)bh * (HD * S_LEN) + (size_t)d * S_LEN + s0 + tx * 8) = v;
  }
}

// Flash attention, causal (unchanged from R6). Block = 64 q-rows (4 waves x
// 16); K/V LDS double-buffered, one barrier/tile; swapped QK^T in-lane
// softmax; T5 setprio around MFMA clusters.
__global__ __launch_bounds__(256, 3) void attn_fwd(const unsigned short* __restrict__ qkv,
                                                   const unsigned short* __restrict__ vt,
                                                   unsigned short* __restrict__ aout) {
  __shared__ unsigned short Ks[2][64 * 64];
  __shared__ unsigned short Vs[2][64 * 64];
  __shared__ unsigned short Pbuf[4][16][72];
  const int bid = blockIdx.x;
  const int qt = 31 - (bid >> 5);
  const int bh = bid & 31;
  const int h = bh & 15, b = bh >> 4;
  const int tid = threadIdx.x, w = tid >> 6, lane = tid & 63;
  const int lr = lane & 15, lk = lane >> 4;
  const int qb = qt * 64 + w * 16;
  const size_t rowbase = (size_t)b * S_LEN;
  const unsigned short* kbase = qkv + rowbase * QKV_LD + DM + h * HD;
  const unsigned short* vbase = vt + (size_t)bh * (HD * S_LEN);

  const int r8 = lane >> 3, c8 = lane & 7;
  const int celem = ((c8 ^ r8) << 3);
  const int swz = (lr & 7) << 3;

  s16x8 qf[2];
#pragma unroll
  for (int dk = 0; dk < 2; ++dk) {
    s16x8 q = *(const s16x8*)(qkv + (rowbase + qb + lr) * QKV_LD + h * HD + dk * 32 + lk * 8);
#pragma unroll
    for (int j = 0; j < 8; ++j)
      q[j] = (short)f2bf(bf2f((unsigned short)q[j]) * 0.18033688011112042f);
    qf[dk] = q;
  }

  f32x4 oacc[4] = {};
  float mr = -1e30f, ls = 0.f;

  auto stage = [&](int t, int c) {
    const int k0 = t * 64;
#pragma unroll
    for (int jj = 0; jj < 4; ++jj) {
      const int j = w * 4 + jj;
      if (j < 8)
        gload_lds16(kbase + (size_t)(k0 + j * 8 + r8) * QKV_LD + celem,
                    (char*)Ks[c] + j * 1024);
      else
        gload_lds16(vbase + (size_t)((j - 8) * 8 + r8) * S_LEN + k0 + celem,
                    (char*)Vs[c] + (j - 8) * 1024);
    }
  };

  stage(0, 0);
  __syncthreads();
  int c = 0;

  for (int t = 0; t <= qt; ++t) {
    if (t < qt) stage(t + 1, c ^ 1);

    const bool dtile = (t == qt);
    f32x4 sf[4];
    __builtin_amdgcn_s_setprio(1);
#pragma unroll
    for (int n = 0; n < 4; ++n) {
      if (!dtile || n <= w) {
        s16x8 kf0 = *(const s16x8*)(Ks[c] + (n * 16 + lr) * 64 + ((lk * 8) ^ swz));
        s16x8 kf1 = *(const s16x8*)(Ks[c] + (n * 16 + lr) * 64 + ((32 + lk * 8) ^ swz));
        f32x4 s = {};
        s = __builtin_amdgcn_mfma_f32_16x16x32_bf16(kf0, qf[0], s, 0, 0, 0);
        s = __builtin_amdgcn_mfma_f32_16x16x32_bf16(kf1, qf[1], s, 0, 0, 0);
        sf[n] = s;
      } else {
#pragma unroll
        for (int r = 0; r < 4; ++r) sf[n][r] = -1e30f;
      }
    }
    __builtin_amdgcn_s_setprio(0);
    if (dtile) {
#pragma unroll
      for (int r = 0; r < 4; ++r)
        if (lk * 4 + r > lr) sf[w][r] = -1e30f;
    }
    float pm = sf[0][0];
#pragma unroll
    for (int n = 0; n < 4; ++n)
#pragma unroll
      for (int r = 0; r < 4; ++r) pm = fmaxf(pm, sf[n][r]);
    pm = fmaxf(pm, __shfl_xor(pm, 16));
    pm = fmaxf(pm, __shfl_xor(pm, 32));
    if (__any(pm > mr + 8.f)) {
      const float mn = fmaxf(mr, pm);
      const float al = __builtin_amdgcn_exp2f(mr - mn);
      mr = mn;
      ls *= al;
#pragma unroll
      for (int r = 0; r < 4; ++r) {
        const float alq = __shfl(al, lk * 4 + r);
#pragma unroll
        for (int n = 0; n < 4; ++n) oacc[n][r] *= alq;
      }
    }
    float rs = 0.f;
#pragma unroll
    for (int n = 0; n < 4; ++n)
#pragma unroll
      for (int r = 0; r < 4; ++r) {
        const float p = __builtin_amdgcn_exp2f(sf[n][r] - mr);
        sf[n][r] = p;
        rs += p;
      }
    rs += __shfl_xor(rs, 16);
    rs += __shfl_xor(rs, 32);
    ls += rs;
#pragma unroll
    for (int n = 0; n < 4; ++n) {
      union { float f; unsigned u; } c0, c1, c2, c3;
      c0.f = sf[n][0]; c1.f = sf[n][1]; c2.f = sf[n][2]; c3.f = sf[n][3];
      uint2 pk;
      pk.x = ((c0.u + 0x8000u) >> 16) | (((c1.u + 0x8000u) >> 16) << 16);
      pk.y = ((c2.u + 0x8000u) >> 16) | (((c3.u + 0x8000u) >> 16) << 16);
      *(uint2*)&Pbuf[w][lr][n * 16 + lk * 4] = pk;
    }
    __builtin_amdgcn_s_setprio(1);
#pragma unroll
    for (int kk = 0; kk < 2; ++kk) {
      s16x8 pf = *(const s16x8*)&Pbuf[w][lr][kk * 32 + lk * 8];
#pragma unroll
      for (int n = 0; n < 4; ++n) {
        s16x8 vf = *(const s16x8*)(Vs[c] + (n * 16 + lr) * 64 + ((kk * 32 + lk * 8) ^ swz));
        oacc[n] = __builtin_amdgcn_mfma_f32_16x16x32_bf16(pf, vf, oacc[n], 0, 0, 0);
      }
    }
    __builtin_amdgcn_s_setprio(0);
    __syncthreads();
    c ^= 1;
  }

  const float rl = __builtin_amdgcn_rcpf(ls);
#pragma unroll
  for (int r = 0; r < 4; ++r) {
    const float rlq = __shfl(rl, lk * 4 + r);
#pragma unroll
    for (int n = 0; n < 4; ++n)
      aout[(rowbase + qb + lk * 4 + r) * DM + h * HD + n * 16 + lr] = f2bf(oacc[n][r] * rlq);
  }
}

extern "C" void kernel_launch(void* const* d_in, const int* in_sizes, int n_in,
                              void* d_out, int out_size, void* d_ws, size_t ws_size,
                              hipStream_t stream) {
  const float* x = (const float*)d_in[0];      // [2,2048,1024]
  const float* wqkv = (const float*)d_in[1];   // [3072,1024]
  const float* wproj = (const float*)d_in[2];  // [1024,1024]
  float* out = (float*)d_out;                  // [2,2048,1024] f32

  char* ws = (char*)d_ws;
  unsigned short* xb = (unsigned short*)ws;                     // dead after gemm1
  unsigned short* wqkvb = (unsigned short*)(ws + (8u << 20));   // dead after gemm1
  unsigned short* wprojb = (unsigned short*)(ws + (14u << 20)); // written after attn
  unsigned short* vtb = (unsigned short*)ws;                    // overlays xb/wqkvb
  unsigned short* qkvb = (unsigned short*)(ws + (16u << 20));
  unsigned short* attnb = (unsigned short*)(ws + (40u << 20));

  cvt_f32_bf16<<<2048, 256, 0, stream>>>(x, xb, 4096 * 1024);
  cvt_f32_bf16<<<1536, 256, 0, stream>>>(wqkv, wqkvb, 3072 * 1024);

  gemm_bt<128, false><<<32 * 24, 256, 0, stream>>>(xb, wqkvb, qkvb, 4096, 3072, 1024, 24);
  vtrans<<<1024, 256, 0, stream>>>(qkvb, vtb);
  attn_fwd<<<1024, 256, 0, stream>>>(qkvb, vtb, attnb);
  cvt_f32_bf16<<<512, 256, 0, stream>>>(wproj, wprojb, 1024 * 1024);
  gemm_bt<64, true><<<32 * 16, 256, 0, stream>>>(attnb, wprojb, out, 4096, 1024, 1024, 16);
}

// Round 10
// 178.378 us; speedup vs baseline: 1.0588x; 1.0226x over previous
//
#include <hip/hip_runtime.h>

#define S_LEN 2048
#define DM 1024
#define NH 16
#define HD 64

using f32x4 = __attribute__((ext_vector_type(4))) float;
using s16x8 = __attribute__((ext_vector_type(8))) short;

__device__ __forceinline__ unsigned short f2bf(float f) {
  union { float f; unsigned u; } v; v.f = f;
  unsigned r = v.u + 0x7fffu + ((v.u >> 16) & 1u);
  return (unsigned short)(r >> 16);
}

__device__ __forceinline__ float bf2f(unsigned short u) {
  union { unsigned u; float f; } v; v.u = ((unsigned)u) << 16;
  return v.f;
}

__device__ __forceinline__ void gload_lds16(const void* g, void* l) {
  __builtin_amdgcn_global_load_lds(
      (const __attribute__((address_space(1))) void*)g,
      (__attribute__((address_space(3))) void*)l, 16, 0, 0);
}

// bijective XCD-aware swizzle (T1); requires nwg % 8 == 0
__device__ __forceinline__ int xcd_swz(int bid, int nwg) {
  const int cpx = nwg >> 3;
  return (bid & 7) * cpx + (bid >> 3);
}

// one kernel converts all three f32 inputs to bf16 (ranges are 256-block aligned)
__global__ __launch_bounds__(256) void cvt_all(const float* __restrict__ x,
                                               const float* __restrict__ wqkv,
                                               const float* __restrict__ wproj,
                                               unsigned short* __restrict__ xb,
                                               unsigned short* __restrict__ wqkvb,
                                               unsigned short* __restrict__ wprojb) {
  int it = blockIdx.x * 256 + threadIdx.x;  // 0 .. 1048575, x8 elements each
  const float* src;
  unsigned short* dst;
  int off;
  if (it < 524288)      { src = x;     dst = xb;     off = it; }
  else if (it < 917504) { src = wqkv;  dst = wqkvb;  off = it - 524288; }
  else                  { src = wproj; dst = wprojb; off = it - 917504; }
  const int i = off * 8;
  float4 a = *(const float4*)(src + i);
  float4 b = *(const float4*)(src + i + 4);
  s16x8 o;
  o[0] = f2bf(a.x); o[1] = f2bf(a.y); o[2] = f2bf(a.z); o[3] = f2bf(a.w);
  o[4] = f2bf(b.x); o[5] = f2bf(b.y); o[6] = f2bf(b.z); o[7] = f2bf(b.w);
  *(s16x8*)(dst + i) = o;
}

// C = A[M,K] * W[N,K]^T. Output written to one of three buffers by col>>10
// (each with row stride 1024): gemm1 splits qkv into Q/K/V buffers; gemm2
// passes the same pointer three times. 128xBN tile, BK=64, 4 waves, m97.
template <int BN, bool OUT_F32>
__global__ __launch_bounds__(256, 3) void gemm_bt(const unsigned short* __restrict__ A,
                                                  const unsigned short* __restrict__ W,
                                                  void* __restrict__ C0,
                                                  void* __restrict__ C1,
                                                  void* __restrict__ C2,
                                                  int M, int N, int K, int nbn) {
  constexpr int FN = BN / 32;
  constexpr int ROUNDS = (128 + BN) / 32;
  __shared__ unsigned short As[128 * 64];
  __shared__ unsigned short Bs[BN * 64];
  const int bid = xcd_swz(blockIdx.x, gridDim.x);
  const int bm = bid / nbn, bn = bid % nbn;
  const int tid = threadIdx.x;
  const int w = tid >> 6, lane = tid & 63;
  const int wr = w >> 1, wc = w & 1;
  const int lr = lane & 15, lk = lane >> 4;
  const int m0 = bm * 128, n0 = bn * BN;
  f32x4 acc[4][FN] = {};

  for (int k0 = 0; k0 < K; k0 += 64) {
#pragma unroll
    for (int j = 0; j < ROUNDS; ++j) {
      const int base = j * 4096 + w * 1024;
      const int boff = base + lane * 16;
      const int row = boff >> 7;
      const int col = (boff >> 1) & 63;
      if (j < 4)
        gload_lds16(A + (size_t)(m0 + row) * K + k0 + col, (char*)As + base);
      else
        gload_lds16(W + (size_t)(n0 + row - 128) * K + k0 + col,
                    (char*)Bs + base - 16384);
    }
    __syncthreads();
#pragma unroll
    for (int kk = 0; kk < 2; ++kk) {
      s16x8 af[4], bfr[FN];
#pragma unroll
      for (int m = 0; m < 4; ++m)
        af[m] = *(const s16x8*)((const char*)As + (wr * 64 + m * 16 + lr) * 128 + kk * 64 + lk * 16);
#pragma unroll
      for (int n = 0; n < FN; ++n)
        bfr[n] = *(const s16x8*)((const char*)Bs + (wc * (FN * 16) + n * 16 + lr) * 128 + kk * 64 + lk * 16);
#pragma unroll
      for (int m = 0; m < 4; ++m)
#pragma unroll
        for (int n = 0; n < FN; ++n)
          acc[m][n] = __builtin_amdgcn_mfma_f32_16x16x32_bf16(af[m], bfr[n], acc[m][n], 0, 0, 0);
    }
    __syncthreads();
  }
  // per-block uniform output-buffer select (BN | 1024 boundaries)
  const int sel = n0 >> 10;
  void* Cs = (sel == 0) ? C0 : (sel == 1) ? C1 : C2;
  const int nb0 = n0 & 1023;
#pragma unroll
  for (int m = 0; m < 4; ++m)
#pragma unroll
    for (int n = 0; n < FN; ++n)
#pragma unroll
      for (int r = 0; r < 4; ++r) {
        const int row = m0 + wr * 64 + m * 16 + lk * 4 + r;
        const int col = nb0 + wc * (FN * 16) + n * 16 + lr;
        if (OUT_F32)
          ((float*)Cs)[(size_t)row * 1024 + col] = acc[m][n][r];
        else
          ((unsigned short*)Cs)[(size_t)row * 1024 + col] = f2bf(acc[m][n][r]);
      }
}

// Transpose V (vraw[B*S][1024], head-major cols) into VT[bh][d][s].
__global__ __launch_bounds__(256) void vtrans(const unsigned short* __restrict__ vraw,
                                              unsigned short* __restrict__ vt) {
  __shared__ unsigned short T[64][65];
  const int blk = blockIdx.x;
  const int st = blk & 31, bh = blk >> 5;
  const int h = bh & 15, b = bh >> 4;
  const int s0 = st * 64;
  const int tid = threadIdx.x;
#pragma unroll
  for (int i = 0; i < 2; ++i) {
    const int idx = tid + i * 256;
    const int sy = idx >> 3, tx = idx & 7;
    s16x8 v = *(const s16x8*)(vraw + (size_t)(b * S_LEN + s0 + sy) * DM + h * HD + tx * 8);
#pragma unroll
    for (int j = 0; j < 8; ++j) T[tx * 8 + j][sy] = v[j];
  }
  __syncthreads();
#pragma unroll
  for (int i = 0; i < 2; ++i) {
    const int idx = tid + i * 256;
    const int d = idx >> 3, tx = idx & 7;
    s16x8 v;
#pragma unroll
    for (int j = 0; j < 8; ++j) v[j] = T[d][tx * 8 + j];
    *(s16x8*)(vt + (size_t)bh * (HD * S_LEN) + (size_t)d * S_LEN + s0 + tx * 8) = v;
  }
}

// Flash attention, causal — EXACT R7-proven kernel; only input pointers
// changed (split Q/K buffers, row stride 1024). Block = 64 q-rows (4 waves x
// 16); K/V LDS double-buffered, one barrier/tile; swapped QK^T in-lane
// softmax; T5 setprio around MFMA clusters.
__global__ __launch_bounds__(256, 3) void attn_fwd(const unsigned short* __restrict__ qb_,
                                                   const unsigned short* __restrict__ kb_,
                                                   const unsigned short* __restrict__ vt,
                                                   unsigned short* __restrict__ aout) {
  __shared__ unsigned short Ks[2][64 * 64];
  __shared__ unsigned short Vs[2][64 * 64];
  __shared__ unsigned short Pbuf[4][16][72];
  const int bid = blockIdx.x;
  const int qt = 31 - (bid >> 5);
  const int bh = bid & 31;
  const int h = bh & 15, b = bh >> 4;
  const int tid = threadIdx.x, w = tid >> 6, lane = tid & 63;
  const int lr = lane & 15, lk = lane >> 4;
  const int qb = qt * 64 + w * 16;
  const size_t rowbase = (size_t)b * S_LEN;
  const unsigned short* kbase = kb_ + rowbase * DM + h * HD;
  const unsigned short* vbase = vt + (size_t)bh * (HD * S_LEN);

  const int r8 = lane >> 3, c8 = lane & 7;
  const int celem = ((c8 ^ r8) << 3);
  const int swz = (lr & 7) << 3;

  s16x8 qf[2];
#pragma unroll
  for (int dk = 0; dk < 2; ++dk) {
    s16x8 q = *(const s16x8*)(qb_ + (rowbase + qb + lr) * DM + h * HD + dk * 32 + lk * 8);
#pragma unroll
    for (int j = 0; j < 8; ++j)
      q[j] = (short)f2bf(bf2f((unsigned short)q[j]) * 0.18033688011112042f);
    qf[dk] = q;
  }

  f32x4 oacc[4] = {};
  float mr = -1e30f, ls = 0.f;

  auto stage = [&](int t, int c) {
    const int k0 = t * 64;
#pragma unroll
    for (int jj = 0; jj < 4; ++jj) {
      const int j = w * 4 + jj;
      if (j < 8)
        gload_lds16(kbase + (size_t)(k0 + j * 8 + r8) * DM + celem,
                    (char*)Ks[c] + j * 1024);
      else
        gload_lds16(vbase + (size_t)((j - 8) * 8 + r8) * S_LEN + k0 + celem,
                    (char*)Vs[c] + (j - 8) * 1024);
    }
  };

  stage(0, 0);
  __syncthreads();
  int c = 0;

  for (int t = 0; t <= qt; ++t) {
    if (t < qt) stage(t + 1, c ^ 1);

    const bool dtile = (t == qt);
    f32x4 sf[4];
    __builtin_amdgcn_s_setprio(1);
#pragma unroll
    for (int n = 0; n < 4; ++n) {
      if (!dtile || n <= w) {
        s16x8 kf0 = *(const s16x8*)(Ks[c] + (n * 16 + lr) * 64 + ((lk * 8) ^ swz));
        s16x8 kf1 = *(const s16x8*)(Ks[c] + (n * 16 + lr) * 64 + ((32 + lk * 8) ^ swz));
        f32x4 s = {};
        s = __builtin_amdgcn_mfma_f32_16x16x32_bf16(kf0, qf[0], s, 0, 0, 0);
        s = __builtin_amdgcn_mfma_f32_16x16x32_bf16(kf1, qf[1], s, 0, 0, 0);
        sf[n] = s;
      } else {
#pragma unroll
        for (int r = 0; r < 4; ++r) sf[n][r] = -1e30f;
      }
    }
    __builtin_amdgcn_s_setprio(0);
    if (dtile) {
#pragma unroll
      for (int r = 0; r < 4; ++r)
        if (lk * 4 + r > lr) sf[w][r] = -1e30f;
    }
    float pm = sf[0][0];
#pragma unroll
    for (int n = 0; n < 4; ++n)
#pragma unroll
      for (int r = 0; r < 4; ++r) pm = fmaxf(pm, sf[n][r]);
    pm = fmaxf(pm, __shfl_xor(pm, 16));
    pm = fmaxf(pm, __shfl_xor(pm, 32));
    if (__any(pm > mr + 8.f)) {
      const float mn = fmaxf(mr, pm);
      const float al = __builtin_amdgcn_exp2f(mr - mn);
      mr = mn;
      ls *= al;
#pragma unroll
      for (int r = 0; r < 4; ++r) {
        const float alq = __shfl(al, lk * 4 + r);
#pragma unroll
        for (int n = 0; n < 4; ++n) oacc[n][r] *= alq;
      }
    }
    float rs = 0.f;
#pragma unroll
    for (int n = 0; n < 4; ++n)
#pragma unroll
      for (int r = 0; r < 4; ++r) {
        const float p = __builtin_amdgcn_exp2f(sf[n][r] - mr);
        sf[n][r] = p;
        rs += p;
      }
    rs += __shfl_xor(rs, 16);
    rs += __shfl_xor(rs, 32);
    ls += rs;
#pragma unroll
    for (int n = 0; n < 4; ++n) {
      union { float f; unsigned u; } c0, c1, c2, c3;
      c0.f = sf[n][0]; c1.f = sf[n][1]; c2.f = sf[n][2]; c3.f = sf[n][3];
      uint2 pk;
      pk.x = ((c0.u + 0x8000u) >> 16) | (((c1.u + 0x8000u) >> 16) << 16);
      pk.y = ((c2.u + 0x8000u) >> 16) | (((c3.u + 0x8000u) >> 16) << 16);
      *(uint2*)&Pbuf[w][lr][n * 16 + lk * 4] = pk;
    }
    __builtin_amdgcn_s_setprio(1);
#pragma unroll
    for (int kk = 0; kk < 2; ++kk) {
      s16x8 pf = *(const s16x8*)&Pbuf[w][lr][kk * 32 + lk * 8];
#pragma unroll
      for (int n = 0; n < 4; ++n) {
        s16x8 vf = *(const s16x8*)(Vs[c] + (n * 16 + lr) * 64 + ((kk * 32 + lk * 8) ^ swz));
        oacc[n] = __builtin_amdgcn_mfma_f32_16x16x32_bf16(pf, vf, oacc[n], 0, 0, 0);
      }
    }
    __builtin_amdgcn_s_setprio(0);
    __syncthreads();
    c ^= 1;
  }

  const float rl = __builtin_amdgcn_rcpf(ls);
#pragma unroll
  for (int r = 0; r < 4; ++r) {
    const float rlq = __shfl(rl, lk * 4 + r);
#pragma unroll
    for (int n = 0; n < 4; ++n)
      aout[(rowbase + qb + lk * 4 + r) * DM + h * HD + n * 16 + lr] = f2bf(oacc[n][r] * rlq);
  }
}

extern "C" void kernel_launch(void* const* d_in, const int* in_sizes, int n_in,
                              void* d_out, int out_size, void* d_ws, size_t ws_size,
                              hipStream_t stream) {
  const float* x = (const float*)d_in[0];      // [2,2048,1024]
  const float* wqkv = (const float*)d_in[1];   // [3072,1024]
  const float* wproj = (const float*)d_in[2];  // [1024,1024]
  float* out = (float*)d_out;                  // [2,2048,1024] f32

  char* ws = (char*)d_ws;
  // layout (48 MB): xb[0,8) wqkvb[8,14) wprojb[14,16) qb[16,24) kb[24,32)
  //                 vraw[32,40) attnb[40,48); vtb (8MB) overlays xb (dead)
  unsigned short* xb = (unsigned short*)ws;
  unsigned short* wqkvb = (unsigned short*)(ws + (8u << 20));
  unsigned short* wprojb = (unsigned short*)(ws + (14u << 20));
  unsigned short* qb = (unsigned short*)(ws + (16u << 20));
  unsigned short* kb = (unsigned short*)(ws + (24u << 20));
  unsigned short* vraw = (unsigned short*)(ws + (32u << 20));
  unsigned short* vtb = (unsigned short*)ws;
  unsigned short* attnb = (unsigned short*)(ws + (40u << 20));

  cvt_all<<<4096, 256, 0, stream>>>(x, wqkv, wproj, xb, wqkvb, wprojb);
  gemm_bt<128, false><<<32 * 24, 256, 0, stream>>>(xb, wqkvb, qb, kb, vraw,
                                                   4096, 3072, 1024, 24);
  vtrans<<<1024, 256, 0, stream>>>(vraw, vtb);
  attn_fwd<<<1024, 256, 0, stream>>>(qb, kb, vtb, attnb);
  gemm_bt<64, true><<<32 * 16, 256, 0, stream>>>(attnb, wprojb, out, out, out,
                                                 4096, 1024, 1024, 16);
}